// Round 6
// baseline (1171.327 us; speedup 1.0000x reference)
//
#include <hip/hip_runtime.h>

// Problem constants (fixed by the reference)
constexpr int Bb = 32;     // batch
constexpr int Tt = 32;     // time steps
constexpr int Ii = 8192;   // input dim
constexpr int Hh = 8192;   // hidden dim
constexpr int Oo = 2048;   // output dim
constexpr int TB = Tt * Bb;  // 1024
constexpr int TCH = 4;       // timesteps per XCD chunk (4 MB x2 slice = 1 XCD L2)

// ELL row strides (entries). Data is a fixed draw (seed 0): realized max row
// nnz ~ lambda + 5 sigma << CAP. Row base r*CAP is pair-aligned (16B) for int4.
constexpr int ELL_IH = 128;  // lambda = 64
constexpr int ELL_HH = 256;  // lambda = 128
constexpr int ELL_HO = 256;  // lambda = 128

// ---------------- x transpose: (B,T,I) -> (I,T,B) ----------------
__global__ void transpose_x_kernel(const float* __restrict__ x, float* __restrict__ x2) {
  // grid = (Tt/2) * (Ii/64) = 2048 blocks, 256 threads
  int blk = blockIdx.x;
  int tp = blk >> 7;             // Ii/64 = 128
  int ib = blk & 127;
  int t0 = tp * 2;
  int i0 = ib * 64;
  __shared__ float lds[64][65];
  int tid = threadIdx.x;
  for (int idx = tid; idx < 64 * 64; idx += 256) {
    int row = idx >> 6;          // tt*32 + b
    int il  = idx & 63;          // coalesced reads along i
    int tt = row >> 5, bb = row & 31;
    lds[il][row] = x[(size_t)bb * Tt * Ii + (size_t)(t0 + tt) * Ii + i0 + il];
  }
  __syncthreads();
  for (int idx = tid; idx < 64 * 64; idx += 256) {
    int il = idx >> 6;
    int row = idx & 63;          // contiguous writes
    x2[(size_t)(i0 + il) * TB + t0 * Bb + row] = lds[il][row];
  }
}

// ---------------- ELL scatter (no hist/scan needed) ----------------
__global__ void scatter3_kernel(
    const int* __restrict__ r1, const int* __restrict__ co1, const float* __restrict__ v1,
    int n1, int* __restrict__ cu1, int2* __restrict__ e1,
    const int* __restrict__ r2, const int* __restrict__ co2, const float* __restrict__ v2,
    int n2, int* __restrict__ cu2, int2* __restrict__ e2,
    const int* __restrict__ r3, const int* __restrict__ co3, const float* __restrict__ v3,
    int n3, int* __restrict__ cu3, int2* __restrict__ e3) {
  int i = blockIdx.x * blockDim.x + threadIdx.x;
  int stride = gridDim.x * blockDim.x;
  for (int j = i; j < n1; j += stride) {
    int r = r1[j];
    int pos = atomicAdd(&cu1[r], 1);
    e1[(size_t)r * ELL_IH + pos] = make_int2(co1[j], __float_as_int(v1[j]));
  }
  for (int j = i; j < n2; j += stride) {
    int r = r2[j];
    int pos = atomicAdd(&cu2[r], 1);
    e2[(size_t)r * ELL_HH + pos] = make_int2(co2[j], __float_as_int(v2[j]));
  }
  for (int j = i; j < n3; j += stride) {
    int r = r3[j];
    int pos = atomicAdd(&cu3[r], 1);
    e3[(size_t)r * ELL_HO + pos] = make_int2(co3[j], __float_as_int(v3[j]));
  }
}

// ---------------- preIH, XCD-pinned time chunks ----------------
// xcd = blockIdx&7 owns t-chunk [TCH*xcd, TCH*xcd+TCH): its 4 MB x2 slice stays
// L2-resident for the whole kernel. Waves within an XCD cover all Hh rows.
// Lane covers (tt = lane>>4, b-pair = 2*(lane&15)) via float2 gathers.
__global__ void __launch_bounds__(256, 8) preih_kernel(
    const int* __restrict__ ih_cnt, const int4* __restrict__ ih_entp,
    const float* __restrict__ hh_bias, const float* __restrict__ x2,
    float* __restrict__ preAll) {
  int xcd = blockIdx.x & 7;
  int r = ((blockIdx.x >> 3) << 2) + (threadIdx.x >> 6);  // 0..Hh-1
  int lane = threadIdx.x & 63;
  int t0 = xcd * TCH;
  int cnt = __builtin_amdgcn_readfirstlane(ih_cnt[r]);
  int np = (cnt + 1) >> 1;                 // pairs; pad slot zeroed
  const int4* ep = ih_entp + (size_t)r * (ELL_IH >> 1);
  const float* xch = x2 + t0 * Bb;         // chunk base; column i at + i*TB

  float2 a0 = {0.f, 0.f}, a1 = {0.f, 0.f}, a2 = {0.f, 0.f}, a3 = {0.f, 0.f};
  int m = 0;
  for (; m + 2 <= np; m += 2) {
    int4 e01 = ep[m];
    int4 e23 = ep[m + 1];
    const float2* p0 = (const float2*)(xch + (size_t)e01.x * TB);
    const float2* p1 = (const float2*)(xch + (size_t)e01.z * TB);
    const float2* p2 = (const float2*)(xch + (size_t)e23.x * TB);
    const float2* p3 = (const float2*)(xch + (size_t)e23.z * TB);
    float2 x0 = p0[lane], x1 = p1[lane], x2v = p2[lane], x3 = p3[lane];
    float v0 = __int_as_float(e01.y), v1 = __int_as_float(e01.w);
    float v2 = __int_as_float(e23.y), v3 = __int_as_float(e23.w);
    a0.x += v0 * x0.x;  a0.y += v0 * x0.y;
    a1.x += v1 * x1.x;  a1.y += v1 * x1.y;
    a2.x += v2 * x2v.x; a2.y += v2 * x2v.y;
    a3.x += v3 * x3.x;  a3.y += v3 * x3.y;
  }
  if (m < np) {
    int4 e01 = ep[m];
    const float2* p0 = (const float2*)(xch + (size_t)e01.x * TB);
    const float2* p1 = (const float2*)(xch + (size_t)e01.z * TB);
    float2 x0 = p0[lane], x1 = p1[lane];
    float v0 = __int_as_float(e01.y), v1 = __int_as_float(e01.w);
    a0.x += v0 * x0.x; a0.y += v0 * x0.y;
    a1.x += v1 * x1.x; a1.y += v1 * x1.y;
  }
  float bias = hh_bias[r];
  float2 acc;
  acc.x = ((a0.x + a1.x) + (a2.x + a3.x)) + bias;
  acc.y = ((a0.y + a1.y) + (a2.y + a3.y)) + bias;
  int t = t0 + (lane >> 4);
  int b0 = (lane & 15) * 2;
  *(float2*)(preAll + ((size_t)t * Hh + r) * Bb + b0) = acc;
}

// ---------------- One recurrence step: h_{t+1} = sigmoid(pre_t + HH @ h_t) ----------------
__global__ void __launch_bounds__(256, 8) step_kernel(
    const int* __restrict__ hh_cnt, const int4* __restrict__ hh_entp,
    const float* __restrict__ pre_t,
    const float* __restrict__ hprev,
    float* __restrict__ hnext) {
  int r = (blockIdx.x * 256 + threadIdx.x) >> 6;   // one wave per row
  int lane = threadIdx.x & 63;
  int h = lane >> 5, b = lane & 31;
  int cnt = __builtin_amdgcn_readfirstlane(hh_cnt[r]);
  int np = (cnt + 1) >> 1;                          // pad pair-half zeroed
  const int4* ep = hh_entp + (size_t)r * (ELL_HH >> 1);
  float pre = pre_t[r * Bb + b];

  float a0 = 0.f, a1 = 0.f, a2 = 0.f, a3 = 0.f;
  int m = 0;
  for (; m + 4 <= np; m += 4) {
    int4 e0 = ep[m];
    int4 e1 = ep[m + 1];
    int4 e2 = ep[m + 2];
    int4 e3 = ep[m + 3];
    int   c0 = h ? e0.z : e0.x;  float v0 = __int_as_float(h ? e0.w : e0.y);
    int   c1 = h ? e1.z : e1.x;  float v1 = __int_as_float(h ? e1.w : e1.y);
    int   c2 = h ? e2.z : e2.x;  float v2 = __int_as_float(h ? e2.w : e2.y);
    int   c3 = h ? e3.z : e3.x;  float v3 = __int_as_float(h ? e3.w : e3.y);
    a0 += v0 * hprev[(c0 << 5) + b];
    a1 += v1 * hprev[(c1 << 5) + b];
    a2 += v2 * hprev[(c2 << 5) + b];
    a3 += v3 * hprev[(c3 << 5) + b];
  }
  for (; m < np; m++) {
    int4 e = ep[m];
    int   c = h ? e.z : e.x;  float v = __int_as_float(h ? e.w : e.y);
    a0 += v * hprev[(c << 5) + b];
  }
  float acc = (a0 + a1) + (a2 + a3);
  acc += __shfl_xor(acc, 32, 64);
  float hv = 1.0f / (1.0f + __expf(-(pre + acc)));
  if (h == 0) hnext[(r << 5) + b] = hv;
}

// ---------------- Output spmm, XCD-partitioned by time ----------------
// xcd = blockIdx&7 owns t-group [4*xcd, 4*xcd+4). Each wave handles an o-row
// for all 4 group timesteps: entry pair loaded once (registers), 4 gathers ->
// per-XCD hot set = 4 h-slices (4 MB, L2-resident) + streamed entries.
__global__ void __launch_bounds__(256, 8) out_kernel(
    const int* __restrict__ ho_cnt, const int4* __restrict__ ho_entp,
    const float* __restrict__ ho_bias, const float* __restrict__ hAll,
    float* __restrict__ out_tmp) {
  int xcd = blockIdx.x & 7;
  int w   = (blockIdx.x >> 3) * 4 + (threadIdx.x >> 6);  // 0..1023 within XCD
  int lane = threadIdx.x & 63;
  int h = lane >> 5, b = lane & 31;
  int t0 = xcd * 4;
  const float* hbase = hAll + (size_t)(t0 + 1) * (Hh * Bb);  // h for step t0
  constexpr size_t HS = (size_t)Hh * Bb;

  for (int o = w; o < Oo; o += 1024) {   // 2 o-rows per wave
    int cnt = __builtin_amdgcn_readfirstlane(ho_cnt[o]);
    int np = (cnt + 1) >> 1;                              // pad slot zeroed
    const int4* ep = ho_entp + (size_t)o * (ELL_HO >> 1);
    float bias = (h == 0) ? ho_bias[o] : 0.f;
    float A0 = bias, A1 = bias, A2 = bias, A3 = bias;
    float B0 = 0.f, B1 = 0.f, B2 = 0.f, B3 = 0.f;
    int m = 0;
    for (; m + 2 <= np; m += 2) {        // 2 pairs -> 8 gathers in flight
      int4 ea = ep[m];
      int4 eb = ep[m + 1];
      int ca = (h ? ea.z : ea.x);  float va = __int_as_float(h ? ea.w : ea.y);
      int cb = (h ? eb.z : eb.x);  float vb = __int_as_float(h ? eb.w : eb.y);
      const float* pa = hbase + ((size_t)ca << 5) + b;
      const float* pb = hbase + ((size_t)cb << 5) + b;
      A0 += va * pa[0];
      A1 += va * pa[HS];
      A2 += va * pa[2 * HS];
      A3 += va * pa[3 * HS];
      B0 += vb * pb[0];
      B1 += vb * pb[HS];
      B2 += vb * pb[2 * HS];
      B3 += vb * pb[3 * HS];
    }
    if (m < np) {
      int4 ea = ep[m];
      int ca = (h ? ea.z : ea.x);  float va = __int_as_float(h ? ea.w : ea.y);
      const float* pa = hbase + ((size_t)ca << 5) + b;
      A0 += va * pa[0];
      A1 += va * pa[HS];
      A2 += va * pa[2 * HS];
      A3 += va * pa[3 * HS];
    }
    A0 += B0; A1 += B1; A2 += B2; A3 += B3;
    A0 += __shfl_xor(A0, 32, 64);
    A1 += __shfl_xor(A1, 32, 64);
    A2 += __shfl_xor(A2, 32, 64);
    A3 += __shfl_xor(A3, 32, 64);
    if (h == 0) {
      out_tmp[((size_t)(t0 + 0) * Oo + o) * Bb + b] = A0;
      out_tmp[((size_t)(t0 + 1) * Oo + o) * Bb + b] = A1;
      out_tmp[((size_t)(t0 + 2) * Oo + o) * Bb + b] = A2;
      out_tmp[((size_t)(t0 + 3) * Oo + o) * Bb + b] = A3;
    }
  }
}

// ---------------- out transpose: (T,O,B) -> (B,T,O) ----------------
__global__ void transpose_out_kernel(const float* __restrict__ out_tmp, float* __restrict__ dout) {
  int blk = blockIdx.x;              // grid = Tt * (Oo/64) = 1024
  int t  = blk >> 5;
  int o0 = (blk & 31) << 6;
  __shared__ float lds[64][33];
  int tid = threadIdx.x;
  for (int idx = tid; idx < 64 * 32; idx += 256) {
    int ol = idx >> 5, bb = idx & 31;
    lds[ol][bb] = out_tmp[(size_t)t * Oo * Bb + (size_t)(o0 + ol) * Bb + bb];
  }
  __syncthreads();
  for (int idx = tid; idx < 32 * 64; idx += 256) {
    int bb = idx >> 6, ol = idx & 63;
    dout[(size_t)bb * Tt * Oo + (size_t)t * Oo + o0 + ol] = lds[ol][bb];
  }
}

extern "C" void kernel_launch(void* const* d_in, const int* in_sizes, int n_in,
                              void* d_out, int out_size, void* d_ws, size_t ws_size,
                              hipStream_t stream) {
  const float* x       = (const float*)d_in[0];
  const int*   hh_rows = (const int*)d_in[1];
  const int*   hh_cols = (const int*)d_in[2];
  const float* hh_vals = (const float*)d_in[3];
  const float* hh_bias = (const float*)d_in[4];
  const int*   ih_rows = (const int*)d_in[5];
  const int*   ih_cols = (const int*)d_in[6];
  const float* ih_vals = (const float*)d_in[7];
  const int*   ho_rows = (const int*)d_in[8];
  const int*   ho_cols = (const int*)d_in[9];
  const float* ho_vals = (const float*)d_in[10];
  const float* ho_bias = (const float*)d_in[11];
  float* out = (float*)d_out;

  const int nnz_hh = in_sizes[1];
  const int nnz_ih = in_sizes[5];
  const int nnz_ho = in_sizes[8];

  // Workspace carve-up (~125 MB)
  char* w = (char*)d_ws;
  size_t off = 0;
  auto alloc = [&](size_t bytes) -> void* {
    void* p = w + off;
    off += (bytes + 255) & ~(size_t)255;
    return p;
  };
  float* x2      = (float*)alloc(sizeof(float) * (size_t)Ii * TB);              // 32 MB
  float* hAll    = (float*)alloc(sizeof(float) * (size_t)(Tt + 1) * Hh * Bb);   // 33 MB
  float* preAll  = (float*)alloc(sizeof(float) * (size_t)Tt * Hh * Bb);         // 32 MB
  int*  cur_all = (int*)alloc(4 * (size_t)(Hh + Hh + Oo));  // contiguous: 1 memset
  int*  ih_cur = cur_all;
  int*  hh_cur = cur_all + Hh;
  int*  ho_cur = cur_all + 2 * Hh;
  size_t ent_off0 = off;
  int2* ih_ent = (int2*)alloc(8 * (size_t)Hh * ELL_IH);     // 8 MB
  int2* hh_ent = (int2*)alloc(8 * (size_t)Hh * ELL_HH);     // 16 MB
  int2* ho_ent = (int2*)alloc(8 * (size_t)Oo * ELL_HO);     // 4 MB
  size_t ent_bytes = off - ent_off0;                        // zero all (pads): 1 memset
  float* out_tmp = x2;   // alias: x2 dead after preih_kernel

  // Init (3 memsets)
  hipMemsetAsync(hAll, 0, sizeof(float) * (size_t)Hh * Bb, stream);   // h_{-1} = 0
  hipMemsetAsync(cur_all, 0, 4 * (size_t)(Hh + Hh + Oo), stream);
  hipMemsetAsync(w + ent_off0, 0, ent_bytes, stream);                 // zero ELL pads

  // x -> (I,T,B)
  transpose_x_kernel<<<(Tt / 2) * (Ii / 64), 256, 0, stream>>>(x, x2);

  // ELL build: single scatter pass (cur becomes per-row count)
  scatter3_kernel<<<1024, 256, 0, stream>>>(
      ih_rows, ih_cols, ih_vals, nnz_ih, ih_cur, ih_ent,
      hh_rows, hh_cols, hh_vals, nnz_hh, hh_cur, hh_ent,
      ho_rows, ho_cols, ho_vals, nnz_ho, ho_cur, ho_ent);

  // pre[t][r][b] for all t; XCD-pinned time chunks (8 chunks = 8 XCDs)
  preih_kernel<<<8 * Hh / 4, 256, 0, stream>>>(
      ih_cur, (const int4*)ih_ent, hh_bias, x2, preAll);

  // Recurrence: one dispatch per step
  for (int t = 0; t < Tt; t++) {
    step_kernel<<<Hh / 4, 256, 0, stream>>>(
        hh_cur, (const int4*)hh_ent,
        preAll + (size_t)t * Hh * Bb,
        hAll + (size_t)t * Hh * Bb,
        hAll + (size_t)(t + 1) * Hh * Bb);
  }

  // Output spmm (XCD t-partitioned) + final transpose
  out_kernel<<<2048, 256, 0, stream>>>(
      ho_cur, (const int4*)ho_ent, ho_bias, hAll, out_tmp);
  transpose_out_kernel<<<Tt * (Oo / 64), 256, 0, stream>>>(out_tmp, out);

  (void)n_in; (void)out_size; (void)ws_size;
}

// Round 7
// 990.486 us; speedup vs baseline: 1.1826x; 1.1826x over previous
//
#include <hip/hip_runtime.h>

// Problem constants (fixed by the reference)
constexpr int Bb = 32;     // batch
constexpr int Tt = 32;     // time steps
constexpr int Ii = 8192;   // input dim
constexpr int Hh = 8192;   // hidden dim
constexpr int Oo = 2048;   // output dim
constexpr int TB = Tt * Bb;  // 1024
constexpr int TCH = 4;       // timesteps per XCD chunk (4 MB x2 slice = 1 XCD L2)

// ---------------- x transpose: (B,T,I) -> (I,T,B) ----------------
__global__ void transpose_x_kernel(const float* __restrict__ x, float* __restrict__ x2) {
  // grid = (Tt/2) * (Ii/64) = 2048 blocks, 256 threads
  int blk = blockIdx.x;
  int tp = blk >> 7;             // Ii/64 = 128
  int ib = blk & 127;
  int t0 = tp * 2;
  int i0 = ib * 64;
  __shared__ float lds[64][65];
  int tid = threadIdx.x;
  for (int idx = tid; idx < 64 * 64; idx += 256) {
    int row = idx >> 6;          // tt*32 + b
    int il  = idx & 63;          // coalesced reads along i
    int tt = row >> 5, bb = row & 31;
    lds[il][row] = x[(size_t)bb * Tt * Ii + (size_t)(t0 + tt) * Ii + i0 + il];
  }
  __syncthreads();
  for (int idx = tid; idx < 64 * 64; idx += 256) {
    int il = idx >> 6;
    int row = idx & 63;          // contiguous writes
    x2[(size_t)(i0 + il) * TB + t0 * Bb + row] = lds[il][row];
  }
}

// ---------------- CSR build (merged kernels) ----------------
__global__ void hist3_kernel(const int* __restrict__ r1, int n1, int* __restrict__ c1,
                             const int* __restrict__ r2, int n2, int* __restrict__ c2,
                             const int* __restrict__ r3, int n3, int* __restrict__ c3) {
  int i = blockIdx.x * blockDim.x + threadIdx.x;
  int stride = gridDim.x * blockDim.x;
  for (int j = i; j < n1; j += stride) atomicAdd(&c1[r1[j]], 1);
  for (int j = i; j < n2; j += stride) atomicAdd(&c2[r2[j]], 1);
  for (int j = i; j < n3; j += stride) atomicAdd(&c3[r3[j]], 1);
}

// Exclusive scan; pad!=0 rounds each row count up to even (16B-aligned row starts
// in the int2 entry array -> int4 pair loads). One block per array.
__global__ void scan3_kernel(int* __restrict__ c1, int n1, int* __restrict__ r1, int p1,
                             int* __restrict__ c2, int n2, int* __restrict__ r2, int p2,
                             int* __restrict__ c3, int n3, int* __restrict__ r3, int p3) {
  int* cnt_cursor; int n; int* row_start; int pad;
  if (blockIdx.x == 0)      { cnt_cursor = c1; n = n1; row_start = r1; pad = p1; }
  else if (blockIdx.x == 1) { cnt_cursor = c2; n = n2; row_start = r2; pad = p2; }
  else                      { cnt_cursor = c3; n = n3; row_start = r3; pad = p3; }
  __shared__ int sums[1024];
  int tid = threadIdx.x;
  int chunk = (n + 1023) >> 10;
  int base = tid * chunk;
  int s = 0;
  for (int i = 0; i < chunk; i++) {
    int idx = base + i;
    if (idx < n) {
      int v = cnt_cursor[idx];
      s += pad ? ((v + 1) & ~1) : v;
    }
  }
  sums[tid] = s;
  __syncthreads();
  for (int off = 1; off < 1024; off <<= 1) {
    int other = (tid >= off) ? sums[tid - off] : 0;
    __syncthreads();
    sums[tid] += other;
    __syncthreads();
  }
  int run = sums[tid] - s;
  for (int i = 0; i < chunk; i++) {
    int idx = base + i;
    if (idx < n) {
      int v = cnt_cursor[idx];
      row_start[idx] = run;
      cnt_cursor[idx] = run;
      run += pad ? ((v + 1) & ~1) : v;
    }
  }
  if (tid == 1023) row_start[n] = sums[1023];
}

__global__ void scatter3_kernel(
    const int* __restrict__ r1, const int* __restrict__ co1, const float* __restrict__ v1,
    int n1, int* __restrict__ cu1, int2* __restrict__ e1,
    const int* __restrict__ r2, const int* __restrict__ co2, const float* __restrict__ v2,
    int n2, int* __restrict__ cu2, int2* __restrict__ e2,
    const int* __restrict__ r3, const int* __restrict__ co3, const float* __restrict__ v3,
    int n3, int* __restrict__ cu3, int2* __restrict__ e3) {
  int i = blockIdx.x * blockDim.x + threadIdx.x;
  int stride = gridDim.x * blockDim.x;
  for (int j = i; j < n1; j += stride) {
    int pos = atomicAdd(&cu1[r1[j]], 1);
    e1[pos] = make_int2(co1[j], __float_as_int(v1[j]));
  }
  for (int j = i; j < n2; j += stride) {
    int pos = atomicAdd(&cu2[r2[j]], 1);
    e2[pos] = make_int2(co2[j], __float_as_int(v2[j]));
  }
  for (int j = i; j < n3; j += stride) {
    int pos = atomicAdd(&cu3[r3[j]], 1);
    e3[pos] = make_int2(co3[j], __float_as_int(v3[j]));
  }
}

// ---------------- preIH, XCD-pinned time chunks + entry prefetch ----------------
// xcd = blockIdx&7 owns t-chunk [TCH*xcd, TCH*xcd+TCH): its 4 MB x2 slice stays
// L2-resident for the whole kernel. CSR entries stream contiguously. Entry
// pairs for iteration m+2 are prefetched during iteration m's gathers, breaking
// the entry->gather dependent-latency chain.
__global__ void __launch_bounds__(256, 8) preih_kernel(
    const int* __restrict__ ih_rs, const int* __restrict__ ih_cur,
    const int4* __restrict__ ih_entp,
    const float* __restrict__ hh_bias, const float* __restrict__ x2,
    float* __restrict__ preAll) {
  int xcd = blockIdx.x & 7;
  int r = ((blockIdx.x >> 3) << 2) + (threadIdx.x >> 6);  // 0..Hh-1
  int lane = threadIdx.x & 63;
  int t0 = xcd * TCH;
  int s0  = __builtin_amdgcn_readfirstlane(ih_rs[r]);       // even (padded)
  int cnt = __builtin_amdgcn_readfirstlane(ih_cur[r]) - s0; // actual entries
  int np = (cnt + 1) >> 1;                                  // pairs; pad slot zeroed
  const int4* ep = ih_entp + (s0 >> 1);
  const float* xch = x2 + t0 * Bb;         // chunk base; column i at + i*TB

  float2 a0 = {0.f, 0.f}, a1 = {0.f, 0.f}, a2 = {0.f, 0.f}, a3 = {0.f, 0.f};
  int4 f0 = ep[0], f1 = ep[1];             // prefetch (overread lands in pad/next rows)
  int m = 0;
  for (; m + 2 <= np; m += 2) {
    int4 e01 = f0;
    int4 e23 = f1;
    f0 = ep[m + 2];                        // prefetch next block during gathers
    f1 = ep[m + 3];
    const float2* p0 = (const float2*)(xch + (size_t)e01.x * TB);
    const float2* p1 = (const float2*)(xch + (size_t)e01.z * TB);
    const float2* p2 = (const float2*)(xch + (size_t)e23.x * TB);
    const float2* p3 = (const float2*)(xch + (size_t)e23.z * TB);
    float2 x0 = p0[lane], x1 = p1[lane], x2v = p2[lane], x3 = p3[lane];
    float v0 = __int_as_float(e01.y), v1 = __int_as_float(e01.w);
    float v2 = __int_as_float(e23.y), v3 = __int_as_float(e23.w);
    a0.x += v0 * x0.x;  a0.y += v0 * x0.y;
    a1.x += v1 * x1.x;  a1.y += v1 * x1.y;
    a2.x += v2 * x2v.x; a2.y += v2 * x2v.y;
    a3.x += v3 * x3.x;  a3.y += v3 * x3.y;
  }
  if (m < np) {
    int4 e01 = f0;
    const float2* p0 = (const float2*)(xch + (size_t)e01.x * TB);
    const float2* p1 = (const float2*)(xch + (size_t)e01.z * TB);
    float2 x0 = p0[lane], x1 = p1[lane];
    float v0 = __int_as_float(e01.y), v1 = __int_as_float(e01.w);
    a0.x += v0 * x0.x; a0.y += v0 * x0.y;
    a1.x += v1 * x1.x; a1.y += v1 * x1.y;
  }
  float bias = hh_bias[r];
  float2 acc;
  acc.x = ((a0.x + a1.x) + (a2.x + a3.x)) + bias;
  acc.y = ((a0.y + a1.y) + (a2.y + a3.y)) + bias;
  int t = t0 + (lane >> 4);
  int b0 = (lane & 15) * 2;
  *(float2*)(preAll + ((size_t)t * Hh + r) * Bb + b0) = acc;
}

// ---------------- One recurrence step: h_{t+1} = sigmoid(pre_t + HH @ h_t) ----------------
// One wave per row; entry pairs for iteration m+4 prefetched during iteration
// m's gathers (registers f0..f3), so gathers wait only on arrived entries.
__global__ void __launch_bounds__(256, 8) step_kernel(
    const int* __restrict__ hh_rs, const int* __restrict__ hh_cur,
    const int4* __restrict__ hh_entp,
    const float* __restrict__ pre_t,
    const float* __restrict__ hprev,
    float* __restrict__ hnext) {
  int r = (blockIdx.x * 256 + threadIdx.x) >> 6;   // one wave per row
  int lane = threadIdx.x & 63;
  int h = lane >> 5, b = lane & 31;
  int s0  = __builtin_amdgcn_readfirstlane(hh_rs[r]);       // even
  int cnt = __builtin_amdgcn_readfirstlane(hh_cur[r]) - s0;
  int np = (cnt + 1) >> 1;                                  // pad pair-half zeroed
  const int4* ep = hh_entp + (s0 >> 1);
  float pre = pre_t[r * Bb + b];

  float a0 = 0.f, a1 = 0.f, a2 = 0.f, a3 = 0.f;
  int4 f0 = ep[0], f1 = ep[1], f2 = ep[2], f3 = ep[3];  // prefetch (pad-safe)
  int m = 0;
  for (; m + 4 <= np; m += 4) {
    int4 e0 = f0, e1 = f1, e2 = f2, e3 = f3;
    f0 = ep[m + 4];                 // prefetch next block during gathers
    f1 = ep[m + 5];
    f2 = ep[m + 6];
    f3 = ep[m + 7];
    int   c0 = h ? e0.z : e0.x;  float v0 = __int_as_float(h ? e0.w : e0.y);
    int   c1 = h ? e1.z : e1.x;  float v1 = __int_as_float(h ? e1.w : e1.y);
    int   c2 = h ? e2.z : e2.x;  float v2 = __int_as_float(h ? e2.w : e2.y);
    int   c3 = h ? e3.z : e3.x;  float v3 = __int_as_float(h ? e3.w : e3.y);
    a0 += v0 * hprev[(c0 << 5) + b];
    a1 += v1 * hprev[(c1 << 5) + b];
    a2 += v2 * hprev[(c2 << 5) + b];
    a3 += v3 * hprev[(c3 << 5) + b];
  }
  for (; m < np; m++) {
    int4 e = ep[m];
    int   c = h ? e.z : e.x;  float v = __int_as_float(h ? e.w : e.y);
    a0 += v * hprev[(c << 5) + b];
  }
  float acc = (a0 + a1) + (a2 + a3);
  acc += __shfl_xor(acc, 32, 64);
  float hv = 1.0f / (1.0f + __expf(-(pre + acc)));
  if (h == 0) hnext[(r << 5) + b] = hv;
}

// ---------------- Output spmm, XCD-partitioned by time ----------------
// xcd = blockIdx&7 owns t-group [4*xcd, 4*xcd+4). Each wave handles an o-row
// for all 4 group timesteps: entry pair loaded once (registers), 4 gathers ->
// per-XCD hot set = 4 h-slices (4 MB, L2-resident) + streamed entries.
__global__ void __launch_bounds__(256, 8) out_kernel(
    const int* __restrict__ ho_rs, const int* __restrict__ ho_cur,
    const int4* __restrict__ ho_entp,
    const float* __restrict__ ho_bias, const float* __restrict__ hAll,
    float* __restrict__ out_tmp) {
  int xcd = blockIdx.x & 7;
  int w   = (blockIdx.x >> 3) * 4 + (threadIdx.x >> 6);  // 0..1023 within XCD
  int lane = threadIdx.x & 63;
  int h = lane >> 5, b = lane & 31;
  int t0 = xcd * 4;
  const float* hbase = hAll + (size_t)(t0 + 1) * (Hh * Bb);  // h for step t0
  constexpr size_t HS = (size_t)Hh * Bb;

  for (int o = w; o < Oo; o += 1024) {   // 2 o-rows per wave
    int s0  = __builtin_amdgcn_readfirstlane(ho_rs[o]);       // even (padded)
    int cnt = __builtin_amdgcn_readfirstlane(ho_cur[o]) - s0;
    int np = (cnt + 1) >> 1;                                  // pad slot zeroed
    const int4* ep = ho_entp + (s0 >> 1);
    float bias = (h == 0) ? ho_bias[o] : 0.f;
    float A0 = bias, A1 = bias, A2 = bias, A3 = bias;
    float B0 = 0.f, B1 = 0.f, B2 = 0.f, B3 = 0.f;
    int m = 0;
    for (; m + 2 <= np; m += 2) {        // 2 pairs -> 8 gathers in flight
      int4 ea = ep[m];
      int4 eb = ep[m + 1];
      int ca = (h ? ea.z : ea.x);  float va = __int_as_float(h ? ea.w : ea.y);
      int cb = (h ? eb.z : eb.x);  float vb = __int_as_float(h ? eb.w : eb.y);
      const float* pa = hbase + ((size_t)ca << 5) + b;
      const float* pb = hbase + ((size_t)cb << 5) + b;
      A0 += va * pa[0];
      A1 += va * pa[HS];
      A2 += va * pa[2 * HS];
      A3 += va * pa[3 * HS];
      B0 += vb * pb[0];
      B1 += vb * pb[HS];
      B2 += vb * pb[2 * HS];
      B3 += vb * pb[3 * HS];
    }
    if (m < np) {
      int4 ea = ep[m];
      int ca = (h ? ea.z : ea.x);  float va = __int_as_float(h ? ea.w : ea.y);
      const float* pa = hbase + ((size_t)ca << 5) + b;
      A0 += va * pa[0];
      A1 += va * pa[HS];
      A2 += va * pa[2 * HS];
      A3 += va * pa[3 * HS];
    }
    A0 += B0; A1 += B1; A2 += B2; A3 += B3;
    A0 += __shfl_xor(A0, 32, 64);
    A1 += __shfl_xor(A1, 32, 64);
    A2 += __shfl_xor(A2, 32, 64);
    A3 += __shfl_xor(A3, 32, 64);
    if (h == 0) {
      out_tmp[((size_t)(t0 + 0) * Oo + o) * Bb + b] = A0;
      out_tmp[((size_t)(t0 + 1) * Oo + o) * Bb + b] = A1;
      out_tmp[((size_t)(t0 + 2) * Oo + o) * Bb + b] = A2;
      out_tmp[((size_t)(t0 + 3) * Oo + o) * Bb + b] = A3;
    }
  }
}

// ---------------- out transpose: (T,O,B) -> (B,T,O) ----------------
__global__ void transpose_out_kernel(const float* __restrict__ out_tmp, float* __restrict__ dout) {
  int blk = blockIdx.x;              // grid = Tt * (Oo/64) = 1024
  int t  = blk >> 5;
  int o0 = (blk & 31) << 6;
  __shared__ float lds[64][33];
  int tid = threadIdx.x;
  for (int idx = tid; idx < 64 * 32; idx += 256) {
    int ol = idx >> 5, bb = idx & 31;
    lds[ol][bb] = out_tmp[(size_t)t * Oo * Bb + (size_t)(o0 + ol) * Bb + bb];
  }
  __syncthreads();
  for (int idx = tid; idx < 32 * 64; idx += 256) {
    int bb = idx >> 6, ol = idx & 63;
    dout[(size_t)bb * Tt * Oo + (size_t)t * Oo + o0 + ol] = lds[ol][bb];
  }
}

extern "C" void kernel_launch(void* const* d_in, const int* in_sizes, int n_in,
                              void* d_out, int out_size, void* d_ws, size_t ws_size,
                              hipStream_t stream) {
  const float* x       = (const float*)d_in[0];
  const int*   hh_rows = (const int*)d_in[1];
  const int*   hh_cols = (const int*)d_in[2];
  const float* hh_vals = (const float*)d_in[3];
  const float* hh_bias = (const float*)d_in[4];
  const int*   ih_rows = (const int*)d_in[5];
  const int*   ih_cols = (const int*)d_in[6];
  const float* ih_vals = (const float*)d_in[7];
  const int*   ho_rows = (const int*)d_in[8];
  const int*   ho_cols = (const int*)d_in[9];
  const float* ho_vals = (const float*)d_in[10];
  const float* ho_bias = (const float*)d_in[11];
  float* out = (float*)d_out;

  const int nnz_hh = in_sizes[1];
  const int nnz_ih = in_sizes[5];
  const int nnz_ho = in_sizes[8];

  // Workspace carve-up
  char* w = (char*)d_ws;
  size_t off = 0;
  auto alloc = [&](size_t bytes) -> void* {
    void* p = w + off;
    off += (bytes + 255) & ~(size_t)255;
    return p;
  };
  float* x2      = (float*)alloc(sizeof(float) * (size_t)Ii * TB);              // 32 MB
  float* hAll    = (float*)alloc(sizeof(float) * (size_t)(Tt + 1) * Hh * Bb);   // 33 MB
  float* preAll  = (float*)alloc(sizeof(float) * (size_t)Tt * Hh * Bb);         // 32 MB
  int*  ih_rs  = (int*)alloc(4 * (size_t)(Hh + 1));
  int*  hh_rs  = (int*)alloc(4 * (size_t)(Hh + 1));
  int*  ho_rs  = (int*)alloc(4 * (size_t)(Oo + 1));
  int*  cur_all = (int*)alloc(4 * (size_t)(Hh + Hh + Oo));  // contiguous: 1 memset
  int*  ih_cur = cur_all;
  int*  hh_cur = cur_all + Hh;
  int*  ho_cur = cur_all + 2 * Hh;
  size_t ent_off0 = off;
  int2* ih_ent = (int2*)alloc(8 * ((size_t)nnz_ih + Hh + 8));   // pair-padded
  int2* hh_ent = (int2*)alloc(8 * ((size_t)nnz_hh + Hh + 8));   // pair-padded
  int2* ho_ent = (int2*)alloc(8 * ((size_t)nnz_ho + Oo + 8));   // pair-padded
  size_t ent_bytes = off - ent_off0;                            // zero all pads: 1 memset
  float* out_tmp = x2;   // alias: x2 dead after preih_kernel

  // Init (3 memsets)
  hipMemsetAsync(hAll, 0, sizeof(float) * (size_t)Hh * Bb, stream);   // h_{-1} = 0
  hipMemsetAsync(cur_all, 0, 4 * (size_t)(Hh + Hh + Oo), stream);
  hipMemsetAsync(w + ent_off0, 0, ent_bytes, stream);                 // zero pad slots

  // x -> (I,T,B)
  transpose_x_kernel<<<(Tt / 2) * (Ii / 64), 256, 0, stream>>>(x, x2);

  // CSR build (all three pair-padded for int4 loads)
  hist3_kernel<<<1024, 256, 0, stream>>>(ih_rows, nnz_ih, ih_cur,
                                         hh_rows, nnz_hh, hh_cur,
                                         ho_rows, nnz_ho, ho_cur);
  scan3_kernel<<<3, 1024, 0, stream>>>(ih_cur, Hh, ih_rs, 1,
                                       hh_cur, Hh, hh_rs, 1,
                                       ho_cur, Oo, ho_rs, 1);
  scatter3_kernel<<<1024, 256, 0, stream>>>(
      ih_rows, ih_cols, ih_vals, nnz_ih, ih_cur, ih_ent,
      hh_rows, hh_cols, hh_vals, nnz_hh, hh_cur, hh_ent,
      ho_rows, ho_cols, ho_vals, nnz_ho, ho_cur, ho_ent);

  // pre[t][r][b] for all t; XCD-pinned time chunks (8 chunks = 8 XCDs), CSR entries
  preih_kernel<<<8 * Hh / 4, 256, 0, stream>>>(
      ih_rs, ih_cur, (const int4*)ih_ent, hh_bias, x2, preAll);

  // Recurrence: one dispatch per step
  for (int t = 0; t < Tt; t++) {
    step_kernel<<<Hh / 4, 256, 0, stream>>>(
        hh_rs, hh_cur, (const int4*)hh_ent,
        preAll + (size_t)t * Hh * Bb,
        hAll + (size_t)t * Hh * Bb,
        hAll + (size_t)(t + 1) * Hh * Bb);
  }

  // Output spmm (XCD t-partitioned) + final transpose
  out_kernel<<<2048, 256, 0, stream>>>(
      ho_rs, ho_cur, (const int4*)ho_ent, ho_bias, hAll, out_tmp);
  transpose_out_kernel<<<Tt * (Oo / 64), 256, 0, stream>>>(out_tmp, out);

  (void)n_in; (void)out_size; (void)ws_size;
}